// Round 2
// baseline (115.659 us; speedup 1.0000x reference)
//
#include <hip/hip_runtime.h>
#include <math.h>

#define B_TOT 16384
#define H     128
#define NC    10
#define NATT  3
#define TR    16      // rows per block; 4 waves split the 128 cols (32 each)
#define HBS   136     // bf16 LDS row stride in ushorts (272B, 16B-aligned)
#define KT    5       // degree-4 minimax of exp on [-1,1]; max err ~5.9e-4
#define EPS   1e-5f
#define EXM_CS 196    // exm copy stride (floats): 16*12+4 -> copies offset by 4 banks
#define EXL_CS 34     // exl copy stride (floats): 16*2+2

typedef __attribute__((ext_vector_type(8))) short bf16x8;
typedef __attribute__((ext_vector_type(4))) float f32x4;

__device__ __forceinline__ ushort f2bf(float f) {
    union { float f; unsigned u; } v; v.f = f;
    unsigned r = v.u + 0x7fffu + ((v.u >> 16) & 1u);   // RNE
    return (ushort)(r >> 16);
}

// tanh(a) = 1 - 2/(e^{2a}+1); saturates correctly for |a| large
__device__ __forceinline__ float fast_tanh(float a) {
    float t = __expf(2.f * a);
    return 1.f - 2.f * __builtin_amdgcn_rcpf(t + 1.f);
}

template<int CTRL>
__device__ __forceinline__ float dpp_add(float v) {
    int x = __float_as_int(v);
    int y = __builtin_amdgcn_update_dpp(0, x, CTRL, 0xf, 0xf, false);
    return v + __int_as_float(y);
}
// all-reduce over the 16 lanes of a DPP row
__device__ __forceinline__ float red16(float v) {
    v = dpp_add<0x121>(v);   // row_ror:1
    v = dpp_add<0x122>(v);   // row_ror:2
    v = dpp_add<0x124>(v);   // row_ror:4
    v = dpp_add<0x128>(v);   // row_ror:8
    return v;
}
// sum of 4 consecutive lanes (mod 16): lane i gets x_i+x_{i+1}+x_{i+2}+x_{i+3}.
// With lane s reading LDS copy (s&3), this sums all 4 wave copies exactly once.
__device__ __forceinline__ float red4ror(float v) {
    v = dpp_add<0x121>(v);   // row_ror:1
    v = dpp_add<0x122>(v);   // row_ror:2
    return v;
}

// ---- prep ----
// wt bf16 mats (layout wt[mat][n][k]):
//   mat0 = W_in^T (unfolded)
//   mat1 = W_att[0]^T (unfolded: layer-0 input h0 has no LN)
//   mat2 = (gamma0 (.) W_att[1])^T      mat3 = (gamma1 (.) W_att[2])^T
//   mat4 = W_c^T padded to 16 rows (unfolded: final LN applied explicitly)
// aux floats at wt+67584, per layer l (stride 512):
//   [0..127]   gw_l[n]  = sum_k gamma_{l-1}[k] * W_att[l][k][n]   (0 for l=0)
//   [128..255] c1_l[n]  = sum_k beta_{l-1}[k]  * W_att[l][k][n] + b_att[l][n]
//   [256..383] gp_l[n]  = gamma_{l-1}[n]  (1 for l=0)
//   [384..511] bp_l[n]  = beta_{l-1}[n]   (0 for l=0)
extern "C" __global__ __launch_bounds__(256)
void prep_weights(const float* __restrict__ W_in,
                  const float* __restrict__ W_att,
                  const float* __restrict__ W_c,
                  const float* __restrict__ gamma,
                  const float* __restrict__ beta,
                  const float* __restrict__ b_att,
                  ushort* __restrict__ wt)
{
    int i = blockIdx.x * 256 + threadIdx.x;
    if (i < 65536) {
        int mat = i >> 14, idx = i & 16383;
        int k = idx >> 7, n = idx & 127;
        float v = (mat == 0) ? W_in[idx] : W_att[(mat - 1) * 16384 + idx];
        if (mat >= 2) v *= gamma[(mat - 2) * H + k];
        wt[mat * 16384 + n * H + k] = f2bf(v);
    } else if (i < 65536 + 2048) {
        int idx = i - 65536;
        int n = idx >> 7, k = idx & 127;
        float v = (n < NC) ? W_c[k * NC + n] : 0.f;
        wt[65536 + n * H + k] = f2bf(v);
    } else if (i < 67584 + 1536) {
        int j = i - 67584;            // 1536 aux threads
        int l = j >> 9;               // layer 0..2
        int idx = j & 511;
        int g = idx >> 7;             // 0=gw 1=c1 2=gp 3=bp
        int n = idx & 127;
        float* aux = (float*)(wt + 67584);
        float v;
        if (g == 0) {
            v = 0.f;
            if (l > 0) {
                for (int k = 0; k < H; ++k)
                    v += gamma[(l - 1) * H + k] * W_att[l * 16384 + k * H + n];
            }
        } else if (g == 1) {
            v = b_att[l * H + n];
            if (l > 0) {
                for (int k = 0; k < H; ++k)
                    v += beta[(l - 1) * H + k] * W_att[l * 16384 + k * H + n];
            }
        } else if (g == 2) {
            v = (l == 0) ? 1.f : gamma[(l - 1) * H + n];
        } else {
            v = (l == 0) ? 0.f : beta[(l - 1) * H + n];
        }
        aux[l * 512 + g * 128 + n] = v;
    }
}

extern "C" __global__ __launch_bounds__(256, 4)
void simple_attention_kernel(const float* __restrict__ x,
                             const float* __restrict__ b_in,
                             const float* __restrict__ gamma,
                             const float* __restrict__ beta,
                             const float* __restrict__ b_c,
                             const ushort* __restrict__ wt,
                             float* __restrict__ out)
{
    __shared__ __align__(16) ushort ab[TR * HBS];       // bf16 A-tile (raw y / h)
    __shared__ __align__(16) float  exm[4 * EXM_CS];    // moment exchange
    __shared__ __align__(16) float  exl[4 * EXL_CS];    // LN exchange

    const int tid  = threadIdx.x;
    const int wv   = tid >> 6;          // wave 0..3 owns cols [32wv, 32wv+32)
    const int lane = tid & 63;
    const int s    = lane & 15;
    const int q    = lane >> 4;
    const size_t rowBase = (size_t)blockIdx.x * TR;
    const float* aux = (const float*)(wt + 67584);

    float y[2][4];     // y[t][r]: row 4q+r, col 32wv+16t+s (raw pre-LN value)
    f32x4 acc[2];

    // ---- stage x tile to LDS as bf16 ----
    {
        const float* xp = x + (rowBase + s) * H + 32 * wv + q * 8;
        float4 v0 = *(const float4*)xp;
        float4 v1 = *(const float4*)(xp + 4);
        bf16x8 a;
        a[0] = f2bf(v0.x); a[1] = f2bf(v0.y); a[2] = f2bf(v0.z); a[3] = f2bf(v0.w);
        a[4] = f2bf(v1.x); a[5] = f2bf(v1.y); a[6] = f2bf(v1.z); a[7] = f2bf(v1.w);
        *(bf16x8*)&ab[s * HBS + 32 * wv + q * 8] = a;
    }
    __syncthreads();

    // ---- in_proj GEMM: y = x@W_in + b_in (no LN on h0) ----
    {
        bf16x8 af[4];
        #pragma unroll
        for (int ks = 0; ks < 4; ++ks)
            af[ks] = *(const bf16x8*)&ab[s * HBS + ks * 32 + q * 8];
        #pragma unroll
        for (int t = 0; t < 2; ++t) acc[t] = (f32x4){0.f, 0.f, 0.f, 0.f};
        #pragma unroll
        for (int ks = 0; ks < 4; ++ks) {
            #pragma unroll
            for (int t = 0; t < 2; ++t) {
                bf16x8 b = *(const bf16x8*)&wt[(32 * wv + 16 * t + s) * H + ks * 32 + q * 8];
                acc[t] = __builtin_amdgcn_mfma_f32_16x16x32_bf16(af[ks], b, acc[t], 0, 0, 0);
            }
        }
        __syncthreads();   // all x-tile reads complete before h0 overwrites ab
        #pragma unroll
        for (int t = 0; t < 2; ++t) {
            int n = 32 * wv + 16 * t + s;
            float bi = b_in[n];
            #pragma unroll
            for (int r = 0; r < 4; ++r) {
                y[t][r] = acc[t][r] + bi;
                ab[(4 * q + r) * HBS + n] = f2bf(y[t][r]);
            }
        }
        __syncthreads();
    }

    // degree-4 Chebyshev-truncated minimax of e^v on [-1,1]
    const float cm[KT] = {1.00004478f, 0.99730768f, 0.49919676f, 0.17734736f, 0.04379392f};

    #pragma unroll 1
    for (int layer = 0; layer < NATT; ++layer) {
        const ushort* WT = wt + (size_t)(1 + layer) * 16384;
        const float* AX  = aux + layer * 512;

        // ---- GEMM on raw y (gamma of prev layer folded into WT) ----
        bf16x8 af[4];
        #pragma unroll
        for (int ks = 0; ks < 4; ++ks)
            af[ks] = *(const bf16x8*)&ab[s * HBS + ks * 32 + q * 8];
        #pragma unroll
        for (int t = 0; t < 2; ++t) acc[t] = (f32x4){0.f, 0.f, 0.f, 0.f};
        #pragma unroll
        for (int ks = 0; ks < 4; ++ks) {
            #pragma unroll
            for (int t = 0; t < 2; ++t) {
                bf16x8 b = *(const bf16x8*)&WT[(32 * wv + 16 * t + s) * H + ks * 32 + q * 8];
                acc[t] = __builtin_amdgcn_mfma_f32_16x16x32_bf16(af[ks], b, acc[t], 0, 0, 0);
            }
        }

        // ---- LN stats of prev y (overlaps the MFMAs above) ----
        float mu[4], inv[4], invmu[4];
        if (layer == 0) {
            #pragma unroll
            for (int r = 0; r < 4; ++r) { mu[r] = 0.f; inv[r] = 1.f; invmu[r] = 0.f; }
        } else {
            #pragma unroll
            for (int r = 0; r < 4; ++r) {
                float2 o = *(const float2*)&exl[(s & 3) * EXL_CS + (4 * q + r) * 2];
                float sm = red4ror(o.x), sq = red4ror(o.y);
                mu[r] = sm * (1.f / H);
                float var = sq * (1.f / H) - mu[r] * mu[r];
                inv[r] = rsqrtf(var + EPS);
                invmu[r] = inv[r] * mu[r];
            }
        }

        // ---- u = tanh(inv*acc - inv*mu*gw + c1); hN = (y-mu)*inv*gp + bp ----
        float u[2][4];
        #pragma unroll
        for (int t = 0; t < 2; ++t) {
            int n = 32 * wv + 16 * t + s;
            float gwv = AX[n];
            float c1v = AX[128 + n];
            float gpv = AX[256 + n];
            float bpv = AX[384 + n];
            #pragma unroll
            for (int r = 0; r < 4; ++r) {
                float pre = fmaf(inv[r], acc[t][r], fmaf(-invmu[r], gwv, c1v));
                u[t][r] = fast_tanh(pre);
                float hN = fmaf((y[t][r] - mu[r]) * inv[r], gpv, bpv);
                y[t][r] = hN;   // y now holds this layer's (normalized) input h
            }
        }

        // ---- partial raw moments over this wave's 32 cols ----
        float S[4][KT], T[4][KT - 1];
        #pragma unroll
        for (int r = 0; r < 4; ++r) {
            #pragma unroll
            for (int k = 0; k < KT; ++k) S[r][k] = 0.f;
            #pragma unroll
            for (int k = 0; k < KT - 1; ++k) T[r][k] = 0.f;
        }
        #pragma unroll
        for (int t = 0; t < 2; ++t) {
            #pragma unroll
            for (int r = 0; r < 4; ++r) {
                float uu = u[t][r], hh = y[t][r];
                S[r][0] += hh;
                float p = uu;
                S[r][1] += p * hh; T[r][0] += p;
                #pragma unroll
                for (int k = 2; k < KT; ++k) {
                    p *= uu;
                    S[r][k] += p * hh;
                    T[r][k - 1] += p;
                }
            }
        }
        #pragma unroll
        for (int r = 0; r < 4; ++r) {
            #pragma unroll
            for (int k = 0; k < KT; ++k)     S[r][k] = red16(S[r][k]);
            #pragma unroll
            for (int k = 0; k < KT - 1; ++k) T[r][k] = red16(T[r][k]);
        }
        if (s == 0) {
            #pragma unroll
            for (int r = 0; r < 4; ++r) {
                float* dst = &exm[wv * EXM_CS + (4 * q + r) * 12];
                *(f32x4*)&dst[0] = (f32x4){S[r][0], S[r][1], S[r][2], S[r][3]};
                *(f32x4*)&dst[4] = (f32x4){S[r][4], T[r][0], T[r][1], T[r][2]};
                dst[8] = T[r][3];
            }
        }
        __syncthreads();
        // lane-distributed combine: lane s reads copy (s&3); ror:1+ror:2 sums all 4
        #pragma unroll
        for (int r = 0; r < 4; ++r) {
            const float* src = &exm[(s & 3) * EXM_CS + (4 * q + r) * 12];
            f32x4 c0 = *(const f32x4*)&src[0];
            f32x4 c1 = *(const f32x4*)&src[4];
            float c2 = src[8];
            S[r][0] = red4ror(c0.x) * cm[0];
            S[r][1] = red4ror(c0.y) * cm[1];
            S[r][2] = red4ror(c0.z) * cm[2];
            S[r][3] = red4ror(c0.w) * cm[3];
            S[r][4] = red4ror(c1.x) * cm[4];
            T[r][0] = red4ror(c1.y) * cm[1];
            T[r][1] = red4ror(c1.z) * cm[2];
            T[r][2] = red4ror(c1.w) * cm[3];
            T[r][3] = red4ror(c2)   * cm[4];
        }

        // ---- Horner + residual + LN partials ----
        float ls[4] = {0, 0, 0, 0}, lq[4] = {0, 0, 0, 0};
        #pragma unroll
        for (int t = 0; t < 2; ++t) {
            #pragma unroll
            for (int r = 0; r < 4; ++r) {
                float uu = u[t][r];
                float num = S[r][KT - 1];
                #pragma unroll
                for (int k = KT - 2; k >= 0; --k) num = num * uu + S[r][k];
                float den = T[r][KT - 2];
                #pragma unroll
                for (int k = KT - 3; k >= 0; --k) den = den * uu + T[r][k];
                den = den * uu + 128.f * 1.00004478f;   // c0 * T0
                float yy = y[t][r] + num * __builtin_amdgcn_rcpf(den);
                y[t][r] = yy;                            // raw pre-LN output
                ls[r] += yy; lq[r] += yy * yy;
            }
        }

        if (layer < NATT - 1) {
            // ---- folded epilogue: store RAW y; LN applied algebraically next layer ----
            #pragma unroll
            for (int t = 0; t < 2; ++t) {
                int n = 32 * wv + 16 * t + s;
                #pragma unroll
                for (int r = 0; r < 4; ++r)
                    ab[(4 * q + r) * HBS + n] = f2bf(y[t][r]);
            }
            #pragma unroll
            for (int r = 0; r < 4; ++r) { ls[r] = red16(ls[r]); lq[r] = red16(lq[r]); }
            if (s == 0) {
                #pragma unroll
                for (int r = 0; r < 4; ++r)
                    *(float2*)&exl[wv * EXL_CS + (4 * q + r) * 2] = make_float2(ls[r], lq[r]);
            }
            __syncthreads();
        } else {
            // ---- last layer: explicit LN epilogue (protects final-GEMM accuracy) ----
            #pragma unroll
            for (int r = 0; r < 4; ++r) { ls[r] = red16(ls[r]); lq[r] = red16(lq[r]); }
            if (s == 0) {
                #pragma unroll
                for (int r = 0; r < 4; ++r)
                    *(float2*)&exl[wv * EXL_CS + (4 * q + r) * 2] = make_float2(ls[r], lq[r]);
            }
            __syncthreads();
            float mu2[4], inv2[4];
            #pragma unroll
            for (int r = 0; r < 4; ++r) {
                float2 o = *(const float2*)&exl[(s & 3) * EXL_CS + (4 * q + r) * 2];
                float sm = red4ror(o.x), sq = red4ror(o.y);
                mu2[r] = sm * (1.f / H);
                float var = sq * (1.f / H) - mu2[r] * mu2[r];
                inv2[r] = rsqrtf(var + EPS);
            }
            #pragma unroll
            for (int t = 0; t < 2; ++t) {
                int n = 32 * wv + 16 * t + s;
                float g  = gamma[layer * H + n];
                float be = beta [layer * H + n];
                #pragma unroll
                for (int r = 0; r < 4; ++r) {
                    float hn = (y[t][r] - mu2[r]) * inv2[r] * g + be;
                    ab[(4 * q + r) * HBS + n] = f2bf(hn);
                }
            }
            __syncthreads();
        }
    }

    // ---- final proj: wave 0 computes 16 rows x NC via one MFMA tile ----
    if (wv == 0) {
        const ushort* WC = wt + 4 * 16384;
        f32x4 facc = (f32x4){0.f, 0.f, 0.f, 0.f};
        #pragma unroll
        for (int ks = 0; ks < 4; ++ks) {
            bf16x8 a = *(const bf16x8*)&ab[s * HBS + ks * 32 + q * 8];
            bf16x8 b = *(const bf16x8*)&WC[s * H + ks * 32 + q * 8];
            facc = __builtin_amdgcn_mfma_f32_16x16x32_bf16(a, b, facc, 0, 0, 0);
        }
        if (s < NC) {
            float bc = b_c[s];
            #pragma unroll
            for (int r = 0; r < 4; ++r)
                out[(rowBase + 4 * q + r) * NC + s] = facc[r] + bc;
        }
    }
}

extern "C" void kernel_launch(void* const* d_in, const int* in_sizes, int n_in,
                              void* d_out, int out_size, void* d_ws, size_t ws_size,
                              hipStream_t stream) {
    const float* x     = (const float*)d_in[0];
    const float* W_in  = (const float*)d_in[1];
    const float* b_in  = (const float*)d_in[2];
    const float* W_att = (const float*)d_in[3];
    const float* b_att = (const float*)d_in[4];
    const float* gamma = (const float*)d_in[5];
    const float* beta  = (const float*)d_in[6];
    const float* W_c   = (const float*)d_in[7];
    const float* b_c   = (const float*)d_in[8];
    float* out  = (float*)d_out;
    ushort* wt  = (ushort*)d_ws;    // bf16 mats (67584 ushorts) + 1536 aux floats

    hipLaunchKernelGGL(prep_weights, dim3(270), dim3(256), 0, stream,
                       W_in, W_att, W_c, gamma, beta, b_att, wt);
    hipLaunchKernelGGL(simple_attention_kernel, dim3(B_TOT / TR), dim3(256), 0, stream,
                       x, b_in, gamma, beta, b_c, wt, out);
}